// Round 1
// baseline (127.597 us; speedup 1.0000x reference)
//
#include <hip/hip_runtime.h>

// QuantumTextClassifier: embed+PE -> 4x {q=cumprod(cos(x)); x=LN(x+q); x=LN(x+q)}
// -> mean over T -> @W + b.
// Mapping: one wave (64 lanes) per row [E=128 -> 2 elems/lane].
// cumprod = wave prefix-product scan; LN = wave shfl_xor reduction.

#define NBLK 4
#define E_DIM 128
#define T_LEN 2048
#define B_SZ 32
#define C_CLS 4
#define LN_EPS 1e-5f
#define WG_PER_B 64   // workgroups per batch element
#define WAVES_PER_WG 4

__device__ __forceinline__ void ln_pair(float y0, float y1,
                                        float g0, float g1v, float be0, float be1,
                                        float& o0, float& o1) {
    // fused mean / mean-of-squares reduction over the 128 row elements
    float s  = y0 + y1;
    float s2 = y0 * y0 + y1 * y1;
    #pragma unroll
    for (int m = 1; m < 64; m <<= 1) {
        s  += __shfl_xor(s,  m);
        s2 += __shfl_xor(s2, m);
    }
    float mu  = s  * (1.0f / 128.0f);
    float var = s2 * (1.0f / 128.0f) - mu * mu;
    float r   = rsqrtf(var + LN_EPS);
    o0 = (y0 - mu) * r * g0  + be0;
    o1 = (y1 - mu) * r * g1v + be1;
}

__global__ __launch_bounds__(256) void qtc_main(
    const int*   __restrict__ tokens,   // [B, T]
    const float* __restrict__ emb,      // [V, E]
    const float* __restrict__ g1,       // [NBLK, E]
    const float* __restrict__ b1,
    const float* __restrict__ g2,
    const float* __restrict__ b2,
    float*       __restrict__ pooled)   // [B, E] accumulator (pre-zeroed)
{
    const int lane = threadIdx.x & 63;
    const int wave = threadIdx.x >> 6;
    const int b    = blockIdx.x / WG_PER_B;
    const int wgb  = blockIdx.x % WG_PER_B;
    const int e0   = 2 * lane;

    // LN params: per-block constants, hoisted into registers
    float G1[NBLK][2], B1[NBLK][2], G2[NBLK][2], B2[NBLK][2];
    #pragma unroll
    for (int i = 0; i < NBLK; ++i) {
        G1[i][0] = g1[i * E_DIM + e0]; G1[i][1] = g1[i * E_DIM + e0 + 1];
        B1[i][0] = b1[i * E_DIM + e0]; B1[i][1] = b1[i * E_DIM + e0 + 1];
        G2[i][0] = g2[i * E_DIM + e0]; G2[i][1] = g2[i * E_DIM + e0 + 1];
        B2[i][0] = b2[i * E_DIM + e0]; B2[i][1] = b2[i * E_DIM + e0 + 1];
    }

    // sinusoidal PE: for elem pair (2*lane, 2*lane+1): i = lane,
    // div = exp(-(2*lane) * ln(10000)/128); pe_even = sin(t*div), pe_odd = cos(t*div)
    const float dfac = expf(-(float)e0 * (9.210340371976184f / 128.0f));

    float sum0 = 0.0f, sum1 = 0.0f;

    for (int t = wgb * WAVES_PER_WG + wave; t < T_LEN; t += WG_PER_B * WAVES_PER_WG) {
        const int tok = tokens[b * T_LEN + t];
        const float2 xv = *reinterpret_cast<const float2*>(&emb[tok * E_DIM + e0]);
        const float ang = (float)t * dfac;
        float x0 = xv.x + sinf(ang);
        float x1 = xv.y + cosf(ang);

        #pragma unroll
        for (int i = 0; i < NBLK; ++i) {
            // q = cumprod(cos(x)) along E
            const float c0 = cosf(x0);
            const float c1 = cosf(x1);
            const float p  = c0 * c1;
            float s = p;
            #pragma unroll
            for (int d = 1; d < 64; d <<= 1) {
                float v = __shfl_up(s, d);
                if (lane >= d) s *= v;
            }
            float excl = __shfl_up(s, 1);
            if (lane == 0) excl = 1.0f;
            const float q0 = excl * c0;   // inclusive prefix through elem e0
            const float q1 = excl * p;    // inclusive prefix through elem e0+1

            // x = LN(x + q) twice (same q)
            float y0 = x0 + q0, y1 = x1 + q1;
            ln_pair(y0, y1, G1[i][0], G1[i][1], B1[i][0], B1[i][1], x0, x1);
            y0 = x0 + q0; y1 = x1 + q1;
            ln_pair(y0, y1, G2[i][0], G2[i][1], B2[i][0], B2[i][1], x0, x1);
        }
        sum0 += x0;
        sum1 += x1;
    }

    atomicAdd(&pooled[b * E_DIM + e0],     sum0);
    atomicAdd(&pooled[b * E_DIM + e0 + 1], sum1);
}

__global__ __launch_bounds__(128) void qtc_final(
    const float* __restrict__ pooled,  // [B, E] sums over T
    const float* __restrict__ W,       // [E, C]
    const float* __restrict__ bias,    // [C]
    float*       __restrict__ out)     // [B, C]
{
    const int tid = threadIdx.x;       // 128 = B_SZ * C_CLS
    const int b = tid >> 2;
    const int c = tid & 3;
    float s = 0.0f;
    #pragma unroll 8
    for (int e = 0; e < E_DIM; ++e)
        s += pooled[b * E_DIM + e] * W[e * C_CLS + c];
    out[b * C_CLS + c] = s * (1.0f / (float)T_LEN) + bias[c];
}

extern "C" void kernel_launch(void* const* d_in, const int* in_sizes, int n_in,
                              void* d_out, int out_size, void* d_ws, size_t ws_size,
                              hipStream_t stream) {
    const int*   tokens = (const int*)  d_in[0];
    const float* emb    = (const float*)d_in[1];
    const float* g1     = (const float*)d_in[2];
    const float* b1     = (const float*)d_in[3];
    const float* g2     = (const float*)d_in[4];
    const float* b2     = (const float*)d_in[5];
    // d_in[6] = q_weights: provably unused by the reference
    const float* W      = (const float*)d_in[7];
    const float* bias   = (const float*)d_in[8];
    float* out    = (float*)d_out;
    float* pooled = (float*)d_ws;      // B*E floats = 16 KB

    hipMemsetAsync(pooled, 0, B_SZ * E_DIM * sizeof(float), stream);
    qtc_main<<<B_SZ * WG_PER_B, 256, 0, stream>>>(tokens, emb, g1, b1, g2, b2, pooled);
    qtc_final<<<1, 128, 0, stream>>>(pooled, W, bias, out);
}

// Round 2
// 79.602 us; speedup vs baseline: 1.6029x; 1.6029x over previous
//
#include <hip/hip_runtime.h>

// QuantumTextClassifier: embed+PE -> 4x {q=cumprod(cos(x)); x=LN(x+q); x=LN(x+q)}
// -> mean over T -> @W + b.
// Mapping: one wave (64 lanes) per row [E=128 -> 2 elems/lane].
// cumprod = DPP multiplicative scan (row_shr + row_bcast); LN = DPP add-reduce
// to lane 63 + readlane broadcast. Zero LDS-pipe ops in the hot loop.

#define NBLK 4
#define E_DIM 128
#define T_LEN 2048
#define B_SZ 32
#define C_CLS 4
#define LN_EPS 1e-5f
#define WG_PER_B 64   // workgroups per batch element
#define WAVES_PER_WG 4
#define T_STRIDE (WG_PER_B * WAVES_PER_WG)   // 256 tokens

#define F_ONE 0x3F800000   // bit pattern of 1.0f
#define F_ZERO 0x00000000

// DPP move: returns selected lanes of v per CTRL; lanes with invalid source or
// masked-off rows get OLD (as bit pattern). row granularity = 16 lanes.
template <int CTRL, int RMASK, int OLDBITS>
__device__ __forceinline__ float dppf(float v) {
    return __int_as_float(__builtin_amdgcn_update_dpp(
        OLDBITS, __float_as_int(v), CTRL, RMASK, 0xF, false));
}

// Sum across 64 lanes, result broadcast via readlane(63) -> SGPR.
__device__ __forceinline__ float wave_sum_u(float s) {
    s += dppf<0x111, 0xF, F_ZERO>(s);   // row_shr:1
    s += dppf<0x112, 0xF, F_ZERO>(s);   // row_shr:2
    s += dppf<0x114, 0xF, F_ZERO>(s);   // row_shr:4
    s += dppf<0x118, 0xF, F_ZERO>(s);   // row_shr:8
    s += dppf<0x142, 0xA, F_ZERO>(s);   // row_bcast15 -> rows 1,3
    s += dppf<0x143, 0xC, F_ZERO>(s);   // row_bcast31 -> rows 2,3
    return __int_as_float(__builtin_amdgcn_readlane(__float_as_int(s), 63));
}

__device__ __forceinline__ void ln_pair(float y0, float y1,
                                        float g0, float g1v, float be0, float be1,
                                        float& o0, float& o1) {
    float s  = wave_sum_u(y0 + y1);
    float s2 = wave_sum_u(fmaf(y0, y0, y1 * y1));
    float mu  = s * (1.0f / 128.0f);
    float var = fmaf(s2, 1.0f / 128.0f, -mu * mu);
    float r   = rsqrtf(var + LN_EPS);
    o0 = fmaf((y0 - mu) * r, g0,  be0);
    o1 = fmaf((y1 - mu) * r, g1v, be1);
}

__global__ __launch_bounds__(256) void qtc_main(
    const int*   __restrict__ tokens,   // [B, T]
    const float* __restrict__ emb,      // [V, E]
    const float* __restrict__ g1,       // [NBLK, E]
    const float* __restrict__ b1,
    const float* __restrict__ g2,
    const float* __restrict__ b2,
    float*       __restrict__ pooled)   // [B, E] accumulator (pre-zeroed)
{
    const int lane = threadIdx.x & 63;
    const int wave = threadIdx.x >> 6;
    const int b    = blockIdx.x / WG_PER_B;
    const int wgb  = blockIdx.x % WG_PER_B;
    const int e0   = 2 * lane;

    // LN params: per-block constants, hoisted into registers (32 VGPRs)
    float G1[NBLK][2], B1[NBLK][2], G2[NBLK][2], B2[NBLK][2];
    #pragma unroll
    for (int i = 0; i < NBLK; ++i) {
        G1[i][0] = g1[i * E_DIM + e0]; G1[i][1] = g1[i * E_DIM + e0 + 1];
        B1[i][0] = b1[i * E_DIM + e0]; B1[i][1] = b1[i * E_DIM + e0 + 1];
        G2[i][0] = g2[i * E_DIM + e0]; G2[i][1] = g2[i * E_DIM + e0 + 1];
        B2[i][0] = b2[i * E_DIM + e0]; B2[i][1] = b2[i * E_DIM + e0 + 1];
    }

    // Sinusoidal PE for elem pair (2*lane, 2*lane+1): freq dfac = 1e4^(-2*lane/128).
    // pe_even = sin(t*dfac), pe_odd = cos(t*dfac). Advance t by T_STRIDE per
    // iteration with an angle-addition rotation (4 FMA) instead of sinf/cosf.
    const float dfac = expf(-(float)e0 * (9.210340371976184f / 128.0f));
    const int   t0   = wgb * WAVES_PER_WG + wave;
    float pe_s = sinf((float)t0 * dfac);
    float pe_c = cosf((float)t0 * dfac);
    const float dS = sinf((float)T_STRIDE * dfac);
    const float dC = cosf((float)T_STRIDE * dfac);

    float sum0 = 0.0f, sum1 = 0.0f;

    for (int t = t0; t < T_LEN; t += T_STRIDE) {
        const int tok = tokens[b * T_LEN + t];
        const float2 xv = *reinterpret_cast<const float2*>(&emb[tok * E_DIM + e0]);
        float x0 = xv.x + pe_s;
        float x1 = xv.y + pe_c;
        // rotate PE to next token
        {
            float ns = fmaf(pe_s, dC, pe_c * dS);
            pe_c     = fmaf(pe_c, dC, -pe_s * dS);
            pe_s     = ns;
        }

        #pragma unroll
        for (int i = 0; i < NBLK; ++i) {
            // q = cumprod(cos(x)) along E, via DPP multiplicative scan
            const float c0 = __cosf(x0);
            const float c1 = __cosf(x1);
            const float p  = c0 * c1;
            float s = p;
            s *= dppf<0x111, 0xF, F_ONE>(s);   // row_shr:1
            s *= dppf<0x112, 0xF, F_ONE>(s);   // row_shr:2
            s *= dppf<0x114, 0xF, F_ONE>(s);   // row_shr:4
            s *= dppf<0x118, 0xF, F_ONE>(s);   // row_shr:8
            const float t15 = dppf<0x142, 0xA, F_ONE>(s);  // rows 1,3 <- lane15/47
            s *= t15;
            const float t31 = dppf<0x143, 0xC, F_ONE>(s);  // rows 2,3 <- lane31
            s *= t31;
            // exclusive prefix: shift, patching lanes 0/16/32/48
            float e = dppf<0x111, 0xF, F_ONE>(s);
            const float patch = t15 * t31;     // lane16: P(0:15); 32: P(0:31); 48: P(0:47); 0: 1
            e = ((lane & 15) == 0) ? patch : e;
            const float q0 = e * c0;
            const float q1 = e * p;

            // x = LN(x + q) twice (same q)
            float y0 = x0 + q0, y1 = x1 + q1;
            ln_pair(y0, y1, G1[i][0], G1[i][1], B1[i][0], B1[i][1], x0, x1);
            y0 = x0 + q0; y1 = x1 + q1;
            ln_pair(y0, y1, G2[i][0], G2[i][1], B2[i][0], B2[i][1], x0, x1);
        }
        sum0 += x0;
        sum1 += x1;
    }

    atomicAdd(&pooled[b * E_DIM + e0],     sum0);
    atomicAdd(&pooled[b * E_DIM + e0 + 1], sum1);
}

__global__ __launch_bounds__(128) void qtc_final(
    const float* __restrict__ pooled,  // [B, E] sums over T
    const float* __restrict__ W,       // [E, C]
    const float* __restrict__ bias,    // [C]
    float*       __restrict__ out)     // [B, C]
{
    const int tid = threadIdx.x;       // 128 = B_SZ * C_CLS
    const int b = tid >> 2;
    const int c = tid & 3;
    float s = 0.0f;
    #pragma unroll 8
    for (int e = 0; e < E_DIM; ++e)
        s += pooled[b * E_DIM + e] * W[e * C_CLS + c];
    out[b * C_CLS + c] = s * (1.0f / (float)T_LEN) + bias[c];
}

extern "C" void kernel_launch(void* const* d_in, const int* in_sizes, int n_in,
                              void* d_out, int out_size, void* d_ws, size_t ws_size,
                              hipStream_t stream) {
    const int*   tokens = (const int*)  d_in[0];
    const float* emb    = (const float*)d_in[1];
    const float* g1     = (const float*)d_in[2];
    const float* b1     = (const float*)d_in[3];
    const float* g2     = (const float*)d_in[4];
    const float* b2     = (const float*)d_in[5];
    // d_in[6] = q_weights: provably unused by the reference
    const float* W      = (const float*)d_in[7];
    const float* bias   = (const float*)d_in[8];
    float* out    = (float*)d_out;
    float* pooled = (float*)d_ws;      // B*E floats = 16 KB

    hipMemsetAsync(pooled, 0, B_SZ * E_DIM * sizeof(float), stream);
    qtc_main<<<B_SZ * WG_PER_B, 256, 0, stream>>>(tokens, emb, g1, b1, g2, b2, pooled);
    qtc_final<<<1, 128, 0, stream>>>(pooled, W, bias, out);
}

// Round 3
// 75.578 us; speedup vs baseline: 1.6883x; 1.0532x over previous
//
#include <hip/hip_runtime.h>

// QuantumTextClassifier: embed+PE -> 4x {q=cumprod(cos(x)); x=LN(x+q); x=LN(x+q)}
// -> mean over T -> @W + b.
// Mapping: one wave (64 lanes) per row [E=128 -> 2 elems/lane].
// cumprod = DPP multiplicative scan; LN = FUSED v_add_f32_dpp reduction
// (old=0, bound_ctrl=1) to lane 63 + readlane. Token loop unrolled 2x for ILP.

#define NBLK 4
#define E_DIM 128
#define T_LEN 2048
#define B_SZ 32
#define C_CLS 4
#define LN_EPS 1e-5f
#define WG_PER_B 64   // workgroups per batch element
#define WAVES_PER_WG 4
#define T_STRIDE (WG_PER_B * WAVES_PER_WG)   // 256 tokens

#define F_ONE 0x3F800000   // bit pattern of 1.0f

// DPP move with old-value semantics (for multiplicative scan: invalid lanes
// and masked rows yield OLD bits).
template <int CTRL, int RMASK, int OLDBITS>
__device__ __forceinline__ float dppf(float v) {
    return __int_as_float(__builtin_amdgcn_update_dpp(
        OLDBITS, __float_as_int(v), CTRL, RMASK, 0xF, false));
}

// Fused-add DPP step: invalid source lanes read 0 (bound_ctrl=1), masked-off
// rows keep old (=0) -> plain add is correct and LLVM folds mov_dpp into
// v_add_f32_dpp.
template <int CTRL, int RMASK>
__device__ __forceinline__ float dpp_add(float s) {
    return s + __int_as_float(__builtin_amdgcn_update_dpp(
        0, __float_as_int(s), CTRL, RMASK, 0xF, true));
}

// Sum across 64 lanes -> total in lane 63 -> broadcast via readlane.
__device__ __forceinline__ float wave_sum_u(float s) {
    s = dpp_add<0x111, 0xF>(s);   // row_shr:1
    s = dpp_add<0x112, 0xF>(s);   // row_shr:2
    s = dpp_add<0x114, 0xF>(s);   // row_shr:4
    s = dpp_add<0x118, 0xF>(s);   // row_shr:8
    s = dpp_add<0x142, 0xA>(s);   // row_bcast15 -> rows 1,3
    s = dpp_add<0x143, 0xC>(s);   // row_bcast31 -> rows 2,3
    return __int_as_float(__builtin_amdgcn_readlane(__float_as_int(s), 63));
}

__device__ __forceinline__ void ln_pair(float y0, float y1,
                                        float g0, float g1v, float be0, float be1,
                                        float& o0, float& o1) {
    float s  = wave_sum_u(y0 + y1);
    float s2 = wave_sum_u(fmaf(y0, y0, y1 * y1));
    float mu  = s * (1.0f / 128.0f);
    float var = fmaf(s2, 1.0f / 128.0f, -mu * mu);
    float r   = rsqrtf(var + LN_EPS);
    o0 = fmaf((y0 - mu) * r, g0,  be0);
    o1 = fmaf((y1 - mu) * r, g1v, be1);
}

__global__ __launch_bounds__(256) void qtc_main(
    const int*   __restrict__ tokens,   // [B, T]
    const float* __restrict__ emb,      // [V, E]
    const float* __restrict__ g1,       // [NBLK, E]
    const float* __restrict__ b1,
    const float* __restrict__ g2,
    const float* __restrict__ b2,
    float*       __restrict__ pooled)   // [B, E] accumulator (pre-zeroed)
{
    const int lane = threadIdx.x & 63;
    const int wave = threadIdx.x >> 6;
    const int b    = blockIdx.x / WG_PER_B;
    const int wgb  = blockIdx.x % WG_PER_B;
    const int e0   = 2 * lane;
    const bool row_head = ((lane & 15) == 0);   // hoisted scan-patch predicate

    // LN params: per-block constants, hoisted into registers (32 VGPRs)
    float G1[NBLK][2], B1[NBLK][2], G2[NBLK][2], B2[NBLK][2];
    #pragma unroll
    for (int i = 0; i < NBLK; ++i) {
        G1[i][0] = g1[i * E_DIM + e0]; G1[i][1] = g1[i * E_DIM + e0 + 1];
        B1[i][0] = b1[i * E_DIM + e0]; B1[i][1] = b1[i * E_DIM + e0 + 1];
        G2[i][0] = g2[i * E_DIM + e0]; G2[i][1] = g2[i * E_DIM + e0 + 1];
        B2[i][0] = b2[i * E_DIM + e0]; B2[i][1] = b2[i * E_DIM + e0 + 1];
    }

    // Sinusoidal PE for elem pair (2*lane, 2*lane+1): freq dfac = 1e4^(-2*lane/128).
    // pe_even = sin(t*dfac), pe_odd = cos(t*dfac). Advance t by T_STRIDE per
    // iteration with an angle-addition rotation instead of sinf/cosf.
    const float dfac = expf(-(float)e0 * (9.210340371976184f / 128.0f));
    const int   t0   = wgb * WAVES_PER_WG + wave;
    float pe_s = sinf((float)t0 * dfac);
    float pe_c = cosf((float)t0 * dfac);
    const float dS = sinf((float)T_STRIDE * dfac);
    const float dC = cosf((float)T_STRIDE * dfac);

    float sum0 = 0.0f, sum1 = 0.0f;

    // 8 iterations; unroll 2 -> two independent per-token chains in flight.
    #pragma unroll 2
    for (int t = t0; t < T_LEN; t += T_STRIDE) {
        const int tok = tokens[b * T_LEN + t];
        const float2 xv = *reinterpret_cast<const float2*>(&emb[tok * E_DIM + e0]);
        float x0 = xv.x + pe_s;
        float x1 = xv.y + pe_c;
        // rotate PE to next token
        {
            float ns = fmaf(pe_s, dC, pe_c * dS);
            pe_c     = fmaf(pe_c, dC, -pe_s * dS);
            pe_s     = ns;
        }

        #pragma unroll
        for (int i = 0; i < NBLK; ++i) {
            // q = cumprod(cos(x)) along E, via DPP multiplicative scan
            const float c0 = __cosf(x0);
            const float c1 = __cosf(x1);
            const float p  = c0 * c1;
            float s = p;
            s *= dppf<0x111, 0xF, F_ONE>(s);   // row_shr:1
            s *= dppf<0x112, 0xF, F_ONE>(s);   // row_shr:2
            s *= dppf<0x114, 0xF, F_ONE>(s);   // row_shr:4
            s *= dppf<0x118, 0xF, F_ONE>(s);   // row_shr:8
            const float t15 = dppf<0x142, 0xA, F_ONE>(s);  // rows 1,3 <- lane15/47
            s *= t15;
            const float t31 = dppf<0x143, 0xC, F_ONE>(s);  // rows 2,3 <- lane31
            s *= t31;
            // exclusive prefix: shift, patching lanes 0/16/32/48
            float e = dppf<0x111, 0xF, F_ONE>(s);
            const float patch = t15 * t31;     // lane16: P(0:15); 32: P(0:31); 48: P(0:47); 0: 1
            e = row_head ? patch : e;
            const float q0 = e * c0;
            const float q1 = e * p;

            // x = LN(x + q) twice (same q)
            float y0 = x0 + q0, y1 = x1 + q1;
            ln_pair(y0, y1, G1[i][0], G1[i][1], B1[i][0], B1[i][1], x0, x1);
            y0 = x0 + q0; y1 = x1 + q1;
            ln_pair(y0, y1, G2[i][0], G2[i][1], B2[i][0], B2[i][1], x0, x1);
        }
        sum0 += x0;
        sum1 += x1;
    }

    atomicAdd(&pooled[b * E_DIM + e0],     sum0);
    atomicAdd(&pooled[b * E_DIM + e0 + 1], sum1);
}

__global__ __launch_bounds__(64) void qtc_final(
    const float* __restrict__ pooled,  // [B, E] sums over T
    const float* __restrict__ W,       // [E, C]
    const float* __restrict__ bias,    // [C]
    float*       __restrict__ out)     // [B, C]
{
    const int b    = blockIdx.x;       // one wave per batch element
    const int lane = threadIdx.x;
    const int e0   = 2 * lane;
    const float p0 = pooled[b * E_DIM + e0];
    const float p1 = pooled[b * E_DIM + e0 + 1];
    float acc[C_CLS];
    #pragma unroll
    for (int c = 0; c < C_CLS; ++c)
        acc[c] = fmaf(p0, W[e0 * C_CLS + c], p1 * W[(e0 + 1) * C_CLS + c]);
    #pragma unroll
    for (int c = 0; c < C_CLS; ++c) {
        float s = acc[c];
        s = dpp_add<0x111, 0xF>(s);
        s = dpp_add<0x112, 0xF>(s);
        s = dpp_add<0x114, 0xF>(s);
        s = dpp_add<0x118, 0xF>(s);
        s = dpp_add<0x142, 0xA>(s);
        s = dpp_add<0x143, 0xC>(s);
        acc[c] = s;                    // total lives in lane 63
    }
    if (lane == 63) {
        #pragma unroll
        for (int c = 0; c < C_CLS; ++c)
            out[b * C_CLS + c] = fmaf(acc[c], 1.0f / (float)T_LEN, bias[c]);
    }
}

extern "C" void kernel_launch(void* const* d_in, const int* in_sizes, int n_in,
                              void* d_out, int out_size, void* d_ws, size_t ws_size,
                              hipStream_t stream) {
    const int*   tokens = (const int*)  d_in[0];
    const float* emb    = (const float*)d_in[1];
    const float* g1     = (const float*)d_in[2];
    const float* b1     = (const float*)d_in[3];
    const float* g2     = (const float*)d_in[4];
    const float* b2     = (const float*)d_in[5];
    // d_in[6] = q_weights: provably unused by the reference
    const float* W      = (const float*)d_in[7];
    const float* bias   = (const float*)d_in[8];
    float* out    = (float*)d_out;
    float* pooled = (float*)d_ws;      // B*E floats = 16 KB

    hipMemsetAsync(pooled, 0, B_SZ * E_DIM * sizeof(float), stream);
    qtc_main<<<B_SZ * WG_PER_B, 256, 0, stream>>>(tokens, emb, g1, b1, g2, b2, pooled);
    qtc_final<<<B_SZ, 64, 0, stream>>>(pooled, W, bias, out);
}